// Round 3
// baseline (470.088 us; speedup 1.0000x reference)
//
#include <hip/hip_runtime.h>
#include <hip/hip_bf16.h>

typedef unsigned short u16;

#define Bb  128
#define Ss  200
#define Tt  199   // S-1
#define Dd  128
#define Kk  4
#define NQq 10000
#define NCc 500

__device__ inline float bf2f(u16 u) {
    union { unsigned int i; float f; } x;
    x.i = ((unsigned int)u) << 16;
    return x.f;
}

// mode m: 1 = buffers hold fp32, 0 = buffers hold bf16
__device__ inline float ldf(const void* p, int i, int m) {
    if (m) return ((const float*)p)[i];
    return bf2f(((const u16*)p)[i]);
}

__device__ inline void stf(void* p, int i, int m, float v) {
    if (m) ((float*)p)[i] = v;
    else ((__hip_bfloat16*)p)[i] = __float2bfloat16(v);
}

__device__ inline int clampi(int v, int lo, int hi) {
    return v < lo ? lo : (v > hi ? hi : v);
}

__device__ inline float wave_red(float v) {
#pragma unroll
    for (int m = 32; m >= 1; m >>= 1) v += __shfl_xor(v, m);
    return v;
}

// ---------------- Pd: detect input float storage (fp32 vs bf16) ------------
__global__ __launch_bounds__(256) void p_detect(const void* Eq, int* flag) {
    const int tid = threadIdx.x;
    const u16* q = (const u16*)Eq;
    float mx = 0.f;
    for (int i = tid; i < 4096; i += 256) {
        float a = fabsf(bf2f(q[i]));
        if (!(a == a)) a = 3.0e38f;  // NaN -> huge
        mx = fmaxf(mx, a);
    }
#pragma unroll
    for (int s = 32; s >= 1; s >>= 1) mx = fmaxf(mx, __shfl_xor(mx, s));
    __shared__ float sm[4];
    if ((tid & 63) == 0) sm[tid >> 6] = mx;
    __syncthreads();
    if (tid == 0) {
        float m2 = fmaxf(fmaxf(sm[0], sm[1]), fmaxf(sm[2], sm[3]));
        flag[0] = (m2 > 1.0e6f) ? 1 : 0;   // bf16 data: ~0.5; fp32-as-bf16: ~1e38
    }
}

// ---------------- P0: cs2 (colsum of W_fuse bottom half) + concept norms ----
__global__ __launch_bounds__(128) void p0_prep(const void* Wf, const void* Ec,
                                               const int* mode,
                                               float* cs2, float* cnorm) {
    const int m = mode[0];
    const int tid = threadIdx.x;
    if (blockIdx.x == 0) {
        float s = 0.f;
        for (int r = 0; r < 128; ++r) s += ldf(Wf, (128 + r) * 128 + tid, m);
        cs2[tid] = s;
    } else {
        const int c = blockIdx.x - 1;  // 0..499
        float v = ldf(Ec, c * 128 + tid, m);
        float s = wave_red(v * v);
        __shared__ float tmp[2];
        if ((tid & 63) == 0) tmp[tid >> 6] = s;
        __syncthreads();
        if (tid == 0) cnorm[c] = fmaxf(sqrtf(tmp[0] + tmp[1]), 1e-8f);
    }
}

// ---------------- P1: folded weight prep -----------------------------------
// Bab rows: [0:128)=Wf_top@WA1, [128:256)=WA2, [256:384)=WA3
// Bfg rows: [0:128)=Wf_top@WF3, [128:256)=WF2
__global__ __launch_bounds__(128) void p1_weights(
    const void* Wf, const void* Wa, const void* Wg,
    const void* bfu, const void* ba, const void* bg,
    const int* mode, const float* cs2, float* Bab, float* Bfg,
    float* vA0, float* vA1, float* vF0, float* vF1) {
    const int m = mode[0];
    const int bi = blockIdx.x, tid = threadIdx.x;
    if (bi < 128) {
        float acc = 0.f;
        for (int j = 0; j < 128; ++j)
            acc += ldf(Wf, bi * 128 + j, m) * ldf(Wa, j * 128 + tid, m);
        Bab[bi * 128 + tid] = acc;
    } else if (bi < 256) {
        const int i = bi - 128;
        float acc = 0.f;
        for (int j = 0; j < 128; ++j)
            acc += ldf(Wf, i * 128 + j, m) * ldf(Wg, (256 + j) * 128 + tid, m);
        Bfg[i * 128 + tid] = acc;
    } else if (bi < 512) {
        const int r = bi - 256 + 128;  // 128..383
        Bab[r * 128 + tid] = ldf(Wa, r * 128 + tid, m);
    } else if (bi < 640) {
        const int r = bi - 512 + 128;  // 128..255
        Bfg[r * 128 + tid] = ldf(Wg, r * 128 + tid, m);
    } else if (bi == 640) {
        float a0 = 0.f, a1 = 0.f;
        for (int j = 0; j < 128; ++j) {
            float wv = ldf(Wa, j * 128 + tid, m);
            a0 += ldf(bfu, j, m) * wv;
            a1 += cs2[j] * wv;
        }
        vA0[tid] = a0 + ldf(ba, tid, m);
        vA1[tid] = a1;
    } else {
        float a0 = 0.f, a1 = 0.f;
        for (int j = 0; j < 128; ++j) {
            float wv = ldf(Wg, (256 + j) * 128 + tid, m);
            a0 += ldf(bfu, j, m) * wv;
            a1 += cs2[j] * wv;
        }
        vF0[tid] = a0 + ldf(bg, tid, m);
        vF1[tid] = a1;
    }
}

// ---------------- P2: per-(t,b) gathers + qdiff (one wave per row) ---------
__global__ __launch_bounds__(64) void p2_rows(
    const int* q_seq, const int* ha_seq, const int* it_seq, const int* ut_seq,
    const int* q2c, const int* q2cm,
    const void* Eq, const void* Eqd, const void* Ec,
    const int* mode, const float* cnorm,
    float* scal, int* cidx, int* eidx) {
    const int m = mode[0];
    const int r = blockIdx.x;          // r = t*128 + b
    const int t = r >> 7, b = r & 127;
    const int lane = threadIdx.x;
    const int qt  = q_seq[b * Ss + t];
    const int qt1 = q_seq[b * Ss + t + 1];
    const float qa = ldf(Eq, qt * 128 + lane, m);
    const float qb = ldf(Eq, qt * 128 + 64 + lane, m);
    const float nqc = fmaxf(sqrtf(wave_red(qa * qa + qb * qb)), 1e-8f);
    const int4 cc = ((const int4*)q2c)[qt];
    const int4 mm = ((const int4*)q2cm)[qt];
    const int cks[4] = {clampi(cc.x, 0, NCc - 1), clampi(cc.y, 0, NCc - 1),
                        clampi(cc.z, 0, NCc - 1), clampi(cc.w, 0, NCc - 1)};
    const int ms[4]  = {mm.x, mm.y, mm.z, mm.w};
    float qs = 0.f;
#pragma unroll
    for (int k = 0; k < 4; ++k) {
        const int ck = cks[k];
        float dot = wave_red(qa * ldf(Ec, ck * 128 + lane, m) +
                             qb * ldf(Ec, ck * 128 + 64 + lane, m));
        float cosv = dot / (nqc * cnorm[ck]);
        qs += (float)ms[k] * (0.5f * cosv + 0.5f);
    }
    if (lane == 0) {
        const float qd1 = 10.f / (1.f + __expf(-ldf(Eqd, qt1, m)));
        float4 s0 = make_float4(qd1, qs, (float)ms[0], (float)ms[1]);
        float4 s1 = make_float4((float)ms[2], (float)ms[3], 0.f, 0.f);
        ((float4*)scal)[r * 2]     = s0;
        ((float4*)scal)[r * 2 + 1] = s1;
        ((int4*)cidx)[r] = ((const int4*)q2c)[qt1];
        int4 e;
        e.x = qt;
        e.y = ut_seq[b * Ss + t];
        e.z = ha_seq[b * Ss + t];
        e.w = it_seq[b * Ss + t];
        ((int4*)eidx)[r] = e;
    }
}

// ---------------- P3: GEMM  rows x {K=384 -> absorb | K=256 -> pre_forget} --
__global__ __launch_bounds__(256) void p3_gemm(
    const void* Eq, const void* Eut, const void* Eha, const void* Eit,
    const int* eidx, const int* c_seq, const int* mode,
    const float* Bab, const float* Bfg,
    const float* vA0, const float* vA1, const float* vF0, const float* vF1,
    float* absorb, float* pref) {
    __shared__ float At[64][36];
    __shared__ float Bt[32][128];
    __shared__ int eis[64][4];
    __shared__ float cfs[64];
    const int m = mode[0];
    const int tid = threadIdx.x;
    const int r0 = blockIdx.x * 64;
    const int by = blockIdx.y;
    if (tid < 64) {
        const int r = r0 + tid;
        int4 e = ((const int4*)eidx)[r];
        eis[tid][0] = clampi(e.x, 0, NQq - 1);
        eis[tid][1] = clampi(e.y, 0, 99);
        eis[tid][2] = clampi(e.z, 0, 11);
        eis[tid][3] = clampi(e.w, 0, 99);
        cfs[tid] = (float)c_seq[(r & 127) * Ss + (r >> 7)];
    }
    __syncthreads();
    float acc[4][8];
#pragma unroll
    for (int j = 0; j < 4; ++j)
#pragma unroll
        for (int i = 0; i < 8; ++i) acc[j][i] = 0.f;
    const float* Bm = by ? Bfg : Bab;
    const int ng = by ? 2 : 3;
    const int tx = tid & 15, ty = tid >> 4;
    for (int g = 0; g < ng; ++g) {
        const void* tab;
        int comp;
        if (by == 0) { tab = (g == 0) ? Eq : ((g == 1) ? Eut : Eha); comp = g; }
        else         { tab = (g == 0) ? Eq : Eit; comp = (g == 0) ? 0 : 3; }
        for (int ks = 0; ks < 4; ++ks) {
            {   // A tile: 64 rows x 32 k
                const int row = tid >> 2, seg = tid & 3;
                const int ei = eis[row][comp] * 128 + ks * 32 + seg * 8;
                float* dst = &At[row][seg * 8];
                if (m) {
                    const float4* src = (const float4*)((const float*)tab + ei);
                    float4 v0 = src[0], v1 = src[1];
                    dst[0] = v0.x; dst[1] = v0.y; dst[2] = v0.z; dst[3] = v0.w;
                    dst[4] = v1.x; dst[5] = v1.y; dst[6] = v1.z; dst[7] = v1.w;
                } else {
                    uint4 v = *(const uint4*)((const u16*)tab + ei);
                    dst[0] = bf2f((u16)(v.x & 0xffff)); dst[1] = bf2f((u16)(v.x >> 16));
                    dst[2] = bf2f((u16)(v.y & 0xffff)); dst[3] = bf2f((u16)(v.y >> 16));
                    dst[4] = bf2f((u16)(v.z & 0xffff)); dst[5] = bf2f((u16)(v.z >> 16));
                    dst[6] = bf2f((u16)(v.w & 0xffff)); dst[7] = bf2f((u16)(v.w >> 16));
                }
            }
            {   // B tile: 32 x 128
                const float4* Bm4 = (const float4*)(Bm + (g * 128 + ks * 32) * 128);
                float4* Bt4 = (float4*)&Bt[0][0];
#pragma unroll
                for (int k = 0; k < 4; ++k) Bt4[tid + k * 256] = Bm4[tid + k * 256];
            }
            __syncthreads();
#pragma unroll
            for (int kk = 0; kk < 32; kk += 4) {
                float a_[4][4];
                *(float4*)&a_[0][0] = *(const float4*)&At[ty * 4 + 0][kk];
                *(float4*)&a_[1][0] = *(const float4*)&At[ty * 4 + 1][kk];
                *(float4*)&a_[2][0] = *(const float4*)&At[ty * 4 + 2][kk];
                *(float4*)&a_[3][0] = *(const float4*)&At[ty * 4 + 3][kk];
#pragma unroll
                for (int q = 0; q < 4; ++q) {
                    float4 b0 = *(const float4*)&Bt[kk + q][tx * 8];
                    float4 b1 = *(const float4*)&Bt[kk + q][tx * 8 + 4];
#pragma unroll
                    for (int j = 0; j < 4; ++j) {
                        const float av = a_[j][q];
                        acc[j][0] += av * b0.x; acc[j][1] += av * b0.y;
                        acc[j][2] += av * b0.z; acc[j][3] += av * b0.w;
                        acc[j][4] += av * b1.x; acc[j][5] += av * b1.y;
                        acc[j][6] += av * b1.z; acc[j][7] += av * b1.w;
                    }
                }
            }
            __syncthreads();
        }
    }
    const float* v0 = by ? vF0 : vA0;
    const float* v1 = by ? vF1 : vA1;
    float* outbase = by ? pref : absorb;
#pragma unroll
    for (int j = 0; j < 4; ++j) {
        const int row = ty * 4 + j;
        const int r = r0 + row;
        const float cf = cfs[row];
        float* op = outbase + r * 128 + tx * 8;
#pragma unroll
        for (int i = 0; i < 8; ++i) {
            const int dd = tx * 8 + i;
            op[i] = acc[j][i] + v0[dd] + cf * v1[dd];
        }
    }
}

// ---------------- P4: sequential scan, one block per batch row -------------
__global__ __launch_bounds__(256) void p4_scan(
    const void* Wg, const void* L0,
    const float* absorb, const float* pref,
    const float* scal, const int* cidx, const float* cnorm,
    const void* Ec, const int* mode, void* out) {
    const int m = mode[0];
    const int b = blockIdx.x;
    const int tid = threadIdx.x;
    const int d = tid >> 1, half = tid & 1;
    __shared__ float lp[128];
    __shared__ float red[4][8];
    float w[64];
#pragma unroll
    for (int i = 0; i < 64; ++i)
        w[i] = ldf(Wg, (half * 64 + i) * 128 + d, m);   // WF1[i_global][d]
    float lc = ldf(L0, b * 128 + d, m);
    if (half == 0) lp[d] = lc;
    __syncthreads();

    for (int t = 0; t < Tt; ++t) {
        const int r = t * 128 + b;
        const float pf = pref[r * 128 + d];
        const float ab = absorb[r * 128 + d];
        int4 ci = ((const int4*)cidx)[r];
        const int c0 = clampi(ci.x, 0, NCc - 1), c1 = clampi(ci.y, 0, NCc - 1);
        const int c2 = clampi(ci.z, 0, NCc - 1), c3 = clampi(ci.w, 0, NCc - 1);
        float4 s0 = make_float4(0.f, 0.f, 0.f, 0.f);
        float4 s1 = s0;
        float n0 = 1.f, n1 = 1.f, n2 = 1.f, n3 = 1.f;
        if (tid == 0) {
            s0 = ((const float4*)scal)[r * 2];
            s1 = ((const float4*)scal)[r * 2 + 1];
            n0 = cnorm[c0]; n1 = cnorm[c1]; n2 = cnorm[c2]; n3 = cnorm[c3];
        }
        const float cpa = ldf(Ec, (half ? c2 : c0) * 128 + d, m);
        const float cpb = ldf(Ec, (half ? c3 : c1) * 128 + d, m);
        // matvec lp @ WF1 (this thread's 64-i half)
        const float* lpc = &lp[half * 64];
        float fs = 0.f;
#pragma unroll
        for (int i = 0; i < 64; i += 4) {
            float4 v = *(const float4*)(lpc + i);
            fs += w[i] * v.x + w[i + 1] * v.y + w[i + 2] * v.z + w[i + 3] * v.w;
        }
        fs += __shfl_xor(fs, 1);  // combine the two halves of the pair
        const float forget = 1.f / (1.f + __expf(-(fs + pf)));
        lc = lc * forget + ab;
        // cosine partials: even lanes carry (lc^2, lc*cp0, lc*cp1); odd (0, lc*cp2, lc*cp3)
        float a0 = half ? 0.f : lc * lc;
        float a1 = lc * cpa, a2 = lc * cpb;
#pragma unroll
        for (int mm = 2; mm <= 32; mm <<= 1) {
            a0 += __shfl_xor(a0, mm); a1 += __shfl_xor(a1, mm); a2 += __shfl_xor(a2, mm);
        }
        __syncthreads();   // (A) everyone done reading lp
        if (half == 0) lp[d] = lc;
        const int wv = tid >> 6, lane = tid & 63;
        if (lane == 0)      { red[wv][0] = a0; red[wv][1] = a1; red[wv][2] = a2; }
        else if (lane == 1) { red[wv][3] = a1; red[wv][4] = a2; }
        __syncthreads();   // (B) lp and red ready
        if (tid == 0) {
            const float S1 = red[0][0] + red[1][0] + red[2][0] + red[3][0];
            const float d0 = red[0][1] + red[1][1] + red[2][1] + red[3][1];
            const float d1 = red[0][2] + red[1][2] + red[2][2] + red[3][2];
            const float d2 = red[0][3] + red[1][3] + red[2][3] + red[3][3];
            const float d3 = red[0][4] + red[1][4] + red[2][4] + red[3][4];
            const float inl = 1.f / fmaxf(sqrtf(S1), 1e-8f);
            const float accv = s0.z * (0.5f * d0 * inl / n0 + 0.5f)
                             + s0.w * (0.5f * d1 * inl / n1 + 0.5f)
                             + s1.x * (0.5f * d2 * inl / n2 + 0.5f)
                             + s1.y * (0.5f * d3 * inl / n3 + 0.5f);
            const float logit = s0.x * (accv - s0.y);
            stf(out, b * Ss + t, m, 1.f / (1.f + __expf(-logit)));
        }
    }
    if (tid == 0) stf(out, b * Ss + 199, m, 0.f);
}

extern "C" void kernel_launch(void* const* d_in, const int* in_sizes, int n_in,
                              void* d_out, int out_size, void* d_ws, size_t ws_size,
                              hipStream_t stream) {
    (void)in_sizes; (void)n_in; (void)out_size; (void)ws_size;
    const int* q_seq  = (const int*)d_in[0];
    const int* ha_seq = (const int*)d_in[1];
    const int* c_seq  = (const int*)d_in[2];
    const int* it_seq = (const int*)d_in[3];
    const int* ut_seq = (const int*)d_in[4];
    const int* q2c    = (const int*)d_in[5];
    const int* q2cm   = (const int*)d_in[6];
    const void* Eq   = d_in[7];
    const void* Eqd  = d_in[8];
    const void* Ec   = d_in[9];
    const void* Eit  = d_in[10];
    const void* Eut  = d_in[11];
    const void* Eha  = d_in[12];
    const void* Wf   = d_in[13];
    const void* bfu  = d_in[14];
    const void* Wa   = d_in[15];
    const void* ba   = d_in[16];
    const void* Wg   = d_in[17];
    const void* bg   = d_in[18];
    const void* L0   = d_in[19];

    // workspace layout: mode flag first, small arrays next, 26 MB tail last
    int*   mode   = (int*)d_ws;                 // 16 ints
    float* scal   = (float*)d_ws + 16;          // 199*128*8 = 203776
    int*   cidx   = (int*)(scal + 203776);      // 199*128*4 = 101888
    int*   eidx   = cidx + 101888;              // 101888
    float* Bab    = (float*)(eidx + 101888);    // 384*128 = 49152
    float* Bfg    = Bab + 49152;                // 256*128 = 32768
    float* vA0    = Bfg + 32768;                // 128
    float* vA1    = vA0 + 128;
    float* vF0    = vA1 + 128;
    float* vF1    = vF0 + 128;
    float* cs2    = vF1 + 128;                  // 128
    float* cnorm  = cs2 + 128;                  // 512 (500 used)
    float* absorb = cnorm + 512;                // 199*128*128 = 3260416
    float* pref   = absorb + 3260416;           // 3260416

    hipLaunchKernelGGL(p_detect, dim3(1), dim3(256), 0, stream, Eq, mode);
    hipLaunchKernelGGL(p0_prep, dim3(501), dim3(128), 0, stream, Wf, Ec, mode, cs2, cnorm);
    hipLaunchKernelGGL(p1_weights, dim3(642), dim3(128), 0, stream,
                       Wf, Wa, Wg, bfu, ba, bg, mode, cs2, Bab, Bfg, vA0, vA1, vF0, vF1);
    hipLaunchKernelGGL(p2_rows, dim3(Tt * Bb), dim3(64), 0, stream,
                       q_seq, ha_seq, it_seq, ut_seq, q2c, q2cm,
                       Eq, Eqd, Ec, mode, cnorm, scal, cidx, eidx);
    hipLaunchKernelGGL(p3_gemm, dim3(398, 2), dim3(256), 0, stream,
                       Eq, Eut, Eha, Eit, eidx, c_seq, mode, Bab, Bfg,
                       vA0, vA1, vF0, vF1, absorb, pref);
    hipLaunchKernelGGL(p4_scan, dim3(Bb), dim3(256), 0, stream,
                       Wg, L0, absorb, pref, scal, cidx, cnorm, Ec, mode, d_out);
}